// Round 20
// baseline (197.577 us; speedup 1.0000x reference)
//
#include <hip/hip_runtime.h>
#include <math.h>

#define BB 4
#define CC 64
#define DI 128
#define NS 16
#define LL 9216
#define NT (LL / 64)

// scan decomposition
#define GCH 576
#define LCH 16
#define NSEQ 8192      // B*DI*NS
#define SD  512        // B*DI
#define NG 24
#define GS 24          // NG*GS == GCH

typedef __attribute__((ext_vector_type(8))) short bf16x8;
typedef __attribute__((ext_vector_type(4))) float fx4;
#define MFMA16 __builtin_amdgcn_mfma_f32_16x16x32_bf16

static __device__ __forceinline__ unsigned short f2b(float f) {
  unsigned u = __float_as_uint(f);
  u += 0x7fffu + ((u >> 16) & 1u);
  return (unsigned short)(u >> 16);
}
static __device__ __forceinline__ float b2f(unsigned short s) {
  return __uint_as_float(((unsigned)s) << 16);
}
static __device__ __forceinline__ float silu_f(float x) {
  return x / (1.f + __expf(-x));
}

// powers of e1: a[n] = e1^(n+1)
static __device__ __forceinline__ void powers16(float e1, float* a) {
  float p2 = e1 * e1, p4 = p2 * p2, p8 = p4 * p4;
  a[0] = e1;      a[1] = p2;      a[2] = p2 * e1;      a[3] = p4;
  a[4] = p4 * e1; a[5] = p4 * p2; a[6] = p4 * p2 * e1; a[7] = p8;
  a[8] = p8 * e1; a[9] = p8 * p2; a[10] = p8 * p2 * e1; a[11] = p8 * p4;
  a[12] = p8 * p4 * e1; a[13] = p8 * p4 * p2; a[14] = p8 * p4 * p2 * e1; a[15] = p8 * p8;
}

// dtv = softplus(v); a[16] decay factors. aone: A0==-1 -> e1=sigmoid(-v) free.
static __device__ __forceinline__ float dt_and_a(float v, float A0, bool aone, bool afast,
                                                 const float* __restrict__ Alog, int d,
                                                 float* a) {
  float em = __expf(-fabsf(v));
  float t = 1.f + em;
  float dtv = fmaxf(v, 0.f) + __logf(t);
  if (aone) {
    float e1 = ((v >= 0.f) ? em : 1.f) / t;   // == exp(-dtv)
    powers16(e1, a);
  } else if (afast) {
    powers16(__expf(dtv * A0), a);
  } else {
    #pragma unroll
    for (int n = 0; n < 16; ++n) a[n] = __expf(dtv * -__expf(Alog[d * NS + n]));
  }
  return dtv;
}

// ---- weight bf16 conversion + per-layer A precompute + L0 instance-norm stats ----
__global__ __launch_bounds__(256) void k_cvt(const float* __restrict__ inw1, const float* __restrict__ xpw1,
                                             const float* __restrict__ ow1, const float* __restrict__ pw1,
                                             const float* __restrict__ inw2, const float* __restrict__ xpw2,
                                             const float* __restrict__ ow2, const float* __restrict__ pw2,
                                             const float* __restrict__ alog1, const float* __restrict__ alog2,
                                             const float* __restrict__ x,
                                             unsigned short* __restrict__ wb,
                                             float* __restrict__ prep,
                                             float* __restrict__ stats) {
  int blk = blockIdx.x;
  int tid = threadIdx.x;
  if (blk >= 274) {
    int bc = blk - 274;
    const float* row = x + (size_t)bc * LL;
    float s = 0.f, s2 = 0.f;
    for (int i = tid; i < LL; i += 256) {
      float v = row[i];
      s += v; s2 += v * v;
    }
    #pragma unroll
    for (int o = 32; o > 0; o >>= 1) {
      s += __shfl_down(s, o);
      s2 += __shfl_down(s2, o);
    }
    __shared__ float red[8];
    int w = tid >> 6;
    if ((tid & 63) == 0) { red[w] = s; red[4 + w] = s2; }
    __syncthreads();
    if (tid == 0) {
      float S = red[0] + red[1] + red[2] + red[3];
      float S2 = red[4] + red[5] + red[6] + red[7];
      float m = S * (1.f / LL);
      float var = S2 * (1.f / LL) - m * m;
      stats[bc * 2] = m;
      stats[bc * 2 + 1] = rsqrtf(var + 1e-5f);
    }
    return;
  }
  if (blk >= 272) {
    int layer = blk - 272;
    const float* alog = layer ? alog2 : alog1;
    float* pr = prep + layer * 2304;
    #pragma unroll
    for (int j = 0; j < 8; ++j) {
      int e = tid + 256 * j;
      pr[e] = -__expf(alog[e]);
    }
    if (tid < 128) {
      int d = tid;
      float A0 = -__expf(alog[d * NS]);
      bool afast = true;
      #pragma unroll
      for (int n = 1; n < 16; ++n) {
        float An = -__expf(alog[d * NS + n]);
        afast = afast && (fabsf(An - A0 * (float)(n + 1)) <= 1e-3f * (float)(n + 1) * fabsf(A0));
      }
      bool aone = afast && (A0 == -1.0f);
      pr[2048 + d] = A0;
      pr[2176 + d] = aone ? 2.f : (afast ? 1.f : 0.f);
    }
    return;
  }
  int idx = blk * 256 + tid;
  int layer = idx >= 34816;
  int e = idx - layer * 34816;
  const float* inw = layer ? inw2 : inw1;
  const float* xpw = layer ? xpw2 : xpw1;
  const float* ow = layer ? ow2 : ow1;
  const float* pw = layer ? pw2 : pw1;
  float v;
  if (e < 16384) v = inw[e];
  else if (e < 22528) { int t = e - 16384; int r = t >> 7, c = t & 127; v = (r < 36) ? xpw[r * 128 + c] : 0.f; }
  else if (e < 30720) v = ow[e - 22528];
  else v = pw[e - 30720];
  wb[idx] = f2b(v);
}

// ---- statfin: reduce per-block channel partials -> stats for layer 1 ----
__global__ __launch_bounds__(64) void k_statfin(const float* __restrict__ partials,
                                                float* __restrict__ stats) {
  int bc = blockIdx.x;
  int b = bc >> 6, c = bc & 63;
  int t = threadIdx.x;
  float S = 0.f, S2 = 0.f;
  for (int g = t; g < GCH; g += 64) {
    size_t pbase = ((size_t)(b * GCH + g)) * 128 + c * 2;
    S += partials[pbase];
    S2 += partials[pbase + 1];
  }
  #pragma unroll
  for (int o = 32; o > 0; o >>= 1) {
    S += __shfl_down(S, o);
    S2 += __shfl_down(S2, o);
  }
  if (t == 0) {
    float m = S * (1.f / LL);
    float var = S2 * (1.f / LL) - m * m;
    stats[bc * 2] = m;
    stats[bc * 2 + 1] = rsqrtf(var + 1e-5f);
  }
}

// ---- fused: transpose + IN + relu + LN + in-proj MFMA -> xf_b, xin_b, sz_b=silu(z) ----
__global__ __launch_bounds__(256) void k_fusein(const float* __restrict__ p,
                                                const float* __restrict__ stats,
                                                const float* __restrict__ g,
                                                const float* __restrict__ be,
                                                const unsigned short* __restrict__ w_b,
                                                unsigned short* __restrict__ xf_b,
                                                unsigned short* __restrict__ xin_b,
                                                unsigned short* __restrict__ sz_b) {
  int b = blockIdx.x / NT;
  int l0 = (blockIdx.x % NT) * 64;
  __shared__ float T[64][65];
  __shared__ unsigned short Tb[64][72];
  int li = threadIdx.x & 63;
  int c0 = threadIdx.x >> 6;
  #pragma unroll
  for (int j = 0; j < 16; ++j) {
    int c = c0 * 16 + j;
    float m = stats[(b * CC + c) * 2];
    float rs = stats[(b * CC + c) * 2 + 1];
    float v = p[((size_t)(b * CC + c)) * LL + l0 + li];
    T[li][c] = fmaxf((v - m) * rs, 0.f);
  }
  __syncthreads();
  {
    int row = threadIdx.x >> 2, part = threadIdx.x & 3;
    int ch0 = part * 16;
    float s = 0.f, s2 = 0.f;
    #pragma unroll
    for (int j = 0; j < 16; ++j) {
      float v = T[row][ch0 + j];
      s += v; s2 += v * v;
    }
    s += __shfl_xor(s, 1); s2 += __shfl_xor(s2, 1);
    s += __shfl_xor(s, 2); s2 += __shfl_xor(s2, 2);
    float m = s * (1.f / 64.f);
    float var = s2 * (1.f / 64.f) - m * m;
    float rs = rsqrtf(var + 1e-5f);
    size_t off0 = ((size_t)b * LL + l0 + row) * CC + ch0;
    #pragma unroll
    for (int j4 = 0; j4 < 4; ++j4) {
      float4 v4 = *(float4*)&T[row][ch0 + j4 * 4];
      xf_b[off0 + j4 * 4 + 0] = f2b(v4.x);
      xf_b[off0 + j4 * 4 + 1] = f2b(v4.y);
      xf_b[off0 + j4 * 4 + 2] = f2b(v4.z);
      xf_b[off0 + j4 * 4 + 3] = f2b(v4.w);
      float4 g4 = *(const float4*)&g[ch0 + j4 * 4];
      float4 b4 = *(const float4*)&be[ch0 + j4 * 4];
      Tb[row][ch0 + j4 * 4 + 0] = f2b((v4.x - m) * rs * g4.x + b4.x);
      Tb[row][ch0 + j4 * 4 + 1] = f2b((v4.y - m) * rs * g4.y + b4.y);
      Tb[row][ch0 + j4 * 4 + 2] = f2b((v4.z - m) * rs * g4.z + b4.z);
      Tb[row][ch0 + j4 * 4 + 3] = f2b((v4.w - m) * rs * g4.w + b4.w);
    }
  }
  __syncthreads();
  int lane = threadIdx.x & 63;
  int wv = threadIdx.x >> 6;
  int lr = lane & 15, kg = lane >> 4;
  int m0 = wv * 16;
  int rowg0 = blockIdx.x * 64 + m0;
  bf16x8 a0 = *(const bf16x8*)&Tb[m0 + lr][kg * 8];
  bf16x8 a1 = *(const bf16x8*)&Tb[m0 + lr][32 + kg * 8];
  #pragma unroll
  for (int nt = 0; nt < 16; ++nt) {
    bf16x8 b0 = *(const bf16x8*)&w_b[(size_t)(nt * 16 + lr) * CC + kg * 8];
    bf16x8 b1 = *(const bf16x8*)&w_b[(size_t)(nt * 16 + lr) * CC + 32 + kg * 8];
    fx4 c = {0.f, 0.f, 0.f, 0.f};
    c = MFMA16(a0, b0, c, 0, 0, 0);
    c = MFMA16(a1, b1, c, 0, 0, 0);
    #pragma unroll
    for (int r = 0; r < 4; ++r) {
      int row = rowg0 + kg * 4 + r, col = nt * 16 + lr;
      if (col < 128) xin_b[(size_t)row * DI + col] = f2b(c[r]);
      else           sz_b[(size_t)row * DI + col - 128] = f2b(silu_f(c[r]));
    }
  }
}

// ---- scanAX: LDS-staged xin window + split-K x-proj MFMA + local scan ----
// emits dblC, dts, hlb (bf16), y1b, epb = bf16(afast ? exp(A0*dtpre) : dtpre)
__global__ __launch_bounds__(128) void k_scanAX(const unsigned short* __restrict__ xin_b,
                                                const float* __restrict__ cw,
                                                const float* __restrict__ cb,
                                                const unsigned short* __restrict__ xpw_b,
                                                const float* __restrict__ Alog,
                                                const float* __restrict__ prep,
                                                const float* __restrict__ dtw,
                                                const float* __restrict__ dtbp,
                                                const float* __restrict__ Dp,
                                                float* __restrict__ dblC,
                                                float* __restrict__ dts,
                                                unsigned short* __restrict__ hlb,
                                                unsigned short* __restrict__ y1b,
                                                unsigned short* __restrict__ epb) {
  int g = blockIdx.x % GCH;
  int b = blockIdx.x / GCH;
  __shared__ float dblP[2][16][40];
  __shared__ unsigned short xcS[16][136];
  __shared__ unsigned short xinS[19][136];
  int wv = threadIdx.x >> 6, lane = threadIdx.x & 63;
  int lr = lane & 15, kg = lane >> 4;
  // stage 19-row window (rows g*16-3 .. g*16+15; zeros when l<0)
  {
    const bf16x8 zv8 = {0, 0, 0, 0, 0, 0, 0, 0};
    for (int e = threadIdx.x; e < 304; e += 128) {
      int row = e >> 4, c8 = e & 15;
      int gl = g * LCH - 3 + row;
      bf16x8 v = (gl >= 0) ? *(const bf16x8*)&xin_b[((size_t)b * LL + gl) * DI + c8 * 8] : zv8;
      *(bf16x8*)&xinS[row][c8 * 8] = v;
    }
  }
  __syncthreads();
  {
    fx4 acc[3];
    #pragma unroll
    for (int nt = 0; nt < 3; ++nt) acc[nt] = (fx4){0.f, 0.f, 0.f, 0.f};
    #pragma unroll
    for (int kk = 0; kk < 2; ++kk) {
      int cbase = (wv * 2 + kk) * 32 + kg * 8;
      bf16x8 x3 = *(const bf16x8*)&xinS[3 + lr][cbase];
      bf16x8 x2 = *(const bf16x8*)&xinS[2 + lr][cbase];
      bf16x8 x1 = *(const bf16x8*)&xinS[1 + lr][cbase];
      bf16x8 x0 = *(const bf16x8*)&xinS[0 + lr][cbase];
      bf16x8 a;
      #pragma unroll
      for (int e = 0; e < 8; ++e) {
        int dd = cbase + e;
        float4 w4 = *(const float4*)&cw[dd * 4];
        float v = cb[dd] + b2f((unsigned short)x0[e]) * w4.x + b2f((unsigned short)x1[e]) * w4.y
                + b2f((unsigned short)x2[e]) * w4.z + b2f((unsigned short)x3[e]) * w4.w;
        a[e] = (short)f2b(silu_f(v));
      }
      *(bf16x8*)&xcS[lr][cbase] = a;
      #pragma unroll
      for (int nt = 0; nt < 3; ++nt) {
        bf16x8 bfr = *(const bf16x8*)&xpw_b[(size_t)(nt * 16 + lr) * DI + cbase];
        acc[nt] = MFMA16(a, bfr, acc[nt], 0, 0, 0);
      }
    }
    #pragma unroll
    for (int nt = 0; nt < 3; ++nt)
      #pragma unroll
      for (int r = 0; r < 4; ++r) {
        int col = nt * 16 + lr;
        if (col < 36) dblP[wv][kg * 4 + r][col] = acc[nt][r];
      }
  }
  __syncthreads();
  for (int e = threadIdx.x; e < 576; e += 128) {
    int r = e / 36, c = e - r * 36;
    dblP[0][r][c] += dblP[1][r][c];
  }
  __syncthreads();
  {
    size_t cbase16 = ((size_t)b * LL + g * LCH) * 16;
    #pragma unroll
    for (int j = 0; j < 2; ++j) {
      int e = threadIdx.x + 128 * j;
      dblC[cbase16 + e] = dblP[0][e >> 4][20 + (e & 15)];
    }
  }
  int d = threadIdx.x;
  float A0 = prep[2048 + d];
  int fl = (int)prep[2176 + d];
  bool afast = fl >= 1;
  bool aone = fl == 2;
  float4 w4 = *(const float4*)&dtw[d * 4];
  float dtbv = dtbp[d];
  float Dv = Dp[d];
  float h[16];
  #pragma unroll
  for (int n = 0; n < 16; ++n) h[n] = 0.f;
  float dtsum = 0.f;
  float epre = 1.f;
  size_t sbase = ((size_t)b * LL + g * LCH) * DI + d;
  #pragma unroll 4
  for (int l = 0; l < LCH; ++l) {
    float xcv = b2f(xcS[l][d]);
    float4 qv = *(float4*)&dblP[0][l][0];
    float v = dtbv + qv.x * w4.x + qv.y * w4.y + qv.z * w4.z + qv.w * w4.w;
    float a[16];
    float dtv = dt_and_a(v, A0, aone, afast, Alog, d, a);
    float dx = dtv * xcv;
    dtsum += dtv;
    epre *= a[0];                 // == exp(A0 * dtsum) along the fast path
    float4 b0 = *(float4*)&dblP[0][l][4];
    float4 b1 = *(float4*)&dblP[0][l][8];
    float4 b2 = *(float4*)&dblP[0][l][12];
    float4 b3 = *(float4*)&dblP[0][l][16];
    h[0]  = a[0]  * h[0]  + dx * b0.x;  h[1]  = a[1]  * h[1]  + dx * b0.y;
    h[2]  = a[2]  * h[2]  + dx * b0.z;  h[3]  = a[3]  * h[3]  + dx * b0.w;
    h[4]  = a[4]  * h[4]  + dx * b1.x;  h[5]  = a[5]  * h[5]  + dx * b1.y;
    h[6]  = a[6]  * h[6]  + dx * b1.z;  h[7]  = a[7]  * h[7]  + dx * b1.w;
    h[8]  = a[8]  * h[8]  + dx * b2.x;  h[9]  = a[9]  * h[9]  + dx * b2.y;
    h[10] = a[10] * h[10] + dx * b2.z;  h[11] = a[11] * h[11] + dx * b2.w;
    h[12] = a[12] * h[12] + dx * b3.x;  h[13] = a[13] * h[13] + dx * b3.y;
    h[14] = a[14] * h[14] + dx * b3.z;  h[15] = a[15] * h[15] + dx * b3.w;
    float4 cc0 = *(float4*)&dblP[0][l][20];
    float4 cc1 = *(float4*)&dblP[0][l][24];
    float4 cc2 = *(float4*)&dblP[0][l][28];
    float4 cc3 = *(float4*)&dblP[0][l][32];
    float y0 = h[0] * cc0.x + h[1] * cc0.y + h[2] * cc0.z + h[3] * cc0.w;
    float y1 = h[4] * cc1.x + h[5] * cc1.y + h[6] * cc1.z + h[7] * cc1.w;
    float y2 = h[8] * cc2.x + h[9] * cc2.y + h[10] * cc2.z + h[11] * cc2.w;
    float y3 = h[12] * cc3.x + h[13] * cc3.y + h[14] * cc3.z + h[15] * cc3.w;
    y1b[sbase + (size_t)l * DI] = f2b((y0 + y1) + (y2 + y3) + Dv * xcv);
    epb[sbase + (size_t)l * DI] = f2b(afast ? epre : dtsum);
  }
  dts[(size_t)g * SD + b * DI + d] = dtsum;
  size_t o = (size_t)g * NSEQ + ((size_t)b * DI + d) * NS;
  bf16x8 hv0, hv1;
  #pragma unroll
  for (int n = 0; n < 8; ++n) { hv0[n] = (short)f2b(h[n]); hv1[n] = (short)f2b(h[8 + n]); }
  *(bf16x8*)&hlb[o] = hv0;
  *(bf16x8*)&hlb[o + 8] = hv1;
}

// ---- scan2a: per-group aggregates; writes packed float2 (A,H) ----
__global__ __launch_bounds__(256) void k_scan2a(const float* __restrict__ dts,
                                                const unsigned short* __restrict__ hlb,
                                                const float* __restrict__ prep,
                                                float2* __restrict__ gah) {
  int t = blockIdx.x * 256 + threadIdx.x;   // < NG*NSEQ
  int grp = t >> 13, seq = t & (NSEQ - 1);
  int sd = seq >> 4;
  float An = prep[seq & (DI * NS - 1)];
  float A = 1.f, H = 0.f;
  int c0 = grp * GS;
  #pragma unroll 4
  for (int c = 0; c < GS; ++c) {
    float a = __expf(An * dts[(size_t)(c0 + c) * SD + sd]);
    H = a * H + b2f(hlb[(size_t)(c0 + c) * NSEQ + seq]);
    A *= a;
  }
  gah[t] = make_float2(A, H);
}

// ---- scan2bc: redundant group-prefix + chunk carries (hi out bf16) ----
__global__ __launch_bounds__(256) void k_scan2bc(const float* __restrict__ dts,
                                                 const unsigned short* __restrict__ hlb,
                                                 const float2* __restrict__ gah,
                                                 const float* __restrict__ prep,
                                                 unsigned short* __restrict__ hib) {
  int t = blockIdx.x * 256 + threadIdx.x;   // < NG*NSEQ
  int grp = t >> 13, seq = t & (NSEQ - 1);
  int sd = seq >> 4;
  float An = prep[seq & (DI * NS - 1)];
  float h = 0.f;
  for (int gg = 0; gg < grp; ++gg) {
    float2 ah = gah[gg * NSEQ + seq];
    h = ah.x * h + ah.y;
  }
  int c0 = grp * GS;
  #pragma unroll 4
  for (int c = 0; c < GS; ++c) {
    float a = __expf(An * dts[(size_t)(c0 + c) * SD + sd]);
    hib[(size_t)(c0 + c) * NSEQ + seq] = f2b(h);
    h = a * h + b2f(hlb[(size_t)(c0 + c) * NSEQ + seq]);
  }
}

// ---- scanCO: y = y1 + C.diag(epre^n).hi; *silu(z); out/pr-proj;
//      emits per-block channel (sum,sumsq) partials when addid==0 ----
__global__ __launch_bounds__(128) void k_scanCO(const float* __restrict__ dblC,
                                                const unsigned short* __restrict__ sz_b,
                                                const unsigned short* __restrict__ y1b,
                                                const unsigned short* __restrict__ epb,
                                                const float* __restrict__ Alog,
                                                const float* __restrict__ prep,
                                                const unsigned short* __restrict__ hib,
                                                const unsigned short* __restrict__ ow_b,
                                                const unsigned short* __restrict__ xf_b,
                                                const float* __restrict__ skipv,
                                                const unsigned short* __restrict__ pw_b,
                                                const float* __restrict__ pb,
                                                const float* __restrict__ ident,
                                                float* __restrict__ partials,
                                                float* __restrict__ dst, int addid) {
  int g = blockIdx.x % GCH;
  int b = blockIdx.x / GCH;
  int d = threadIdx.x;
  __shared__ float Cms[LCH * NS];
  __shared__ unsigned short yS[16][136];
  __shared__ unsigned short tmpS[16][72];
  {
    int tid = threadIdx.x;
    size_t cb16 = ((size_t)b * LL + g * LCH) * 16;
    if (tid < 64) *(float4*)&Cms[tid * 4] = *(const float4*)&dblC[cb16 + tid * 4];
  }
  bool afast = ((int)prep[2176 + d]) >= 1;
  __syncthreads();
  size_t o = (size_t)g * NSEQ + ((size_t)b * DI + d) * NS;
  float hiR[16];
  {
    bf16x8 h0 = *(const bf16x8*)&hib[o];
    bf16x8 h1 = *(const bf16x8*)&hib[o + 8];
    #pragma unroll
    for (int n = 0; n < 8; ++n) {
      hiR[n] = b2f((unsigned short)h0[n]);
      hiR[8 + n] = b2f((unsigned short)h1[n]);
    }
  }
  size_t base = ((size_t)b * LL + g * LCH) * DI + d;
  #pragma unroll 4
  for (int l = 0; l < LCH; ++l) {
    float pv = b2f(epb[base + (size_t)l * DI]);   // epre if afast else dtpre
    float y1v = b2f(y1b[base + (size_t)l * DI]);
    float sg = b2f(sz_b[base + (size_t)l * DI]);
    float pw[16];
    if (afast) {
      powers16(pv, pw);
    } else {
      #pragma unroll
      for (int n = 0; n < 16; ++n) pw[n] = __expf(-__expf(Alog[d * NS + n]) * pv);
    }
    float4 c0 = *(float4*)&Cms[l * 16];
    float4 c1 = *(float4*)&Cms[l * 16 + 4];
    float4 c2 = *(float4*)&Cms[l * 16 + 8];
    float4 c3 = *(float4*)&Cms[l * 16 + 12];
    float s0 = c0.x * pw[0] * hiR[0] + c0.y * pw[1] * hiR[1] + c0.z * pw[2] * hiR[2] + c0.w * pw[3] * hiR[3];
    float s1 = c1.x * pw[4] * hiR[4] + c1.y * pw[5] * hiR[5] + c1.z * pw[6] * hiR[6] + c1.w * pw[7] * hiR[7];
    float s2 = c2.x * pw[8] * hiR[8] + c2.y * pw[9] * hiR[9] + c2.z * pw[10] * hiR[10] + c2.w * pw[11] * hiR[11];
    float s3 = c3.x * pw[12] * hiR[12] + c3.y * pw[13] * hiR[13] + c3.z * pw[14] * hiR[14] + c3.w * pw[15] * hiR[15];
    float yv = y1v + ((s0 + s1) + (s2 + s3));
    yS[l][d] = f2b(yv * sg);
  }
  __syncthreads();
  int lane = threadIdx.x & 63;
  int lr = lane & 15, kg = lane >> 4;
  int lw = threadIdx.x >> 6;
  {
    fx4 oacc[2];
    oacc[0] = (fx4){0.f, 0.f, 0.f, 0.f};
    oacc[1] = (fx4){0.f, 0.f, 0.f, 0.f};
    #pragma unroll
    for (int ks = 0; ks < 4; ++ks) {
      int cbase = ks * 32 + kg * 8;
      bf16x8 a = *(const bf16x8*)&yS[lr][cbase];
      #pragma unroll
      for (int j = 0; j < 2; ++j) {
        int nt = lw * 2 + j;
        bf16x8 bfr = *(const bf16x8*)&ow_b[(size_t)(nt * 16 + lr) * DI + cbase];
        oacc[j] = MFMA16(a, bfr, oacc[j], 0, 0, 0);
      }
    }
    float sk = skipv[0];
    #pragma unroll
    for (int j = 0; j < 2; ++j) {
      int nt = lw * 2 + j;
      #pragma unroll
      for (int r = 0; r < 4; ++r) {
        int rowl = kg * 4 + r, col = nt * 16 + lr;
        size_t grow = (size_t)b * LL + g * LCH + rowl;
        tmpS[rowl][col] = f2b(oacc[j][r] + sk * b2f(xf_b[grow * CC + col]));
      }
    }
  }
  __syncthreads();
  {
    fx4 pacc[2];
    pacc[0] = (fx4){0.f, 0.f, 0.f, 0.f};
    pacc[1] = (fx4){0.f, 0.f, 0.f, 0.f};
    #pragma unroll
    for (int ks = 0; ks < 2; ++ks) {
      int cbase = ks * 32 + kg * 8;
      bf16x8 bfrag = *(const bf16x8*)&tmpS[lr][cbase];
      #pragma unroll
      for (int j = 0; j < 2; ++j) {
        int ct = lw * 2 + j;
        bf16x8 a = *(const bf16x8*)&pw_b[(size_t)(ct * 16 + lr) * CC + cbase];
        pacc[j] = MFMA16(a, bfrag, pacc[j], 0, 0, 0);
      }
    }
    #pragma unroll
    for (int j = 0; j < 2; ++j) {
      int ct = lw * 2 + j;
      #pragma unroll
      for (int r = 0; r < 4; ++r) {
        int c = ct * 16 + kg * 4 + r;
        int lpos = g * LCH + lr;
        size_t off = ((size_t)(b * CC + c)) * LL + lpos;
        float val = pacc[j][r] + pb[c];
        if (addid) {
          dst[off] = val + ident[off];
        } else {
          dst[off] = val;
          float s = val, s2 = val * val;
          s += __shfl_xor(s, 1); s2 += __shfl_xor(s2, 1);
          s += __shfl_xor(s, 2); s2 += __shfl_xor(s2, 2);
          s += __shfl_xor(s, 4); s2 += __shfl_xor(s2, 4);
          s += __shfl_xor(s, 8); s2 += __shfl_xor(s2, 8);
          if (lr == 0) {
            size_t pbase = ((size_t)(b * GCH + g)) * 128 + c * 2;
            partials[pbase] = s;
            partials[pbase + 1] = s2;
          }
        }
      }
    }
  }
}

extern "C" void kernel_launch(void* const* d_in, const int* in_sizes, int n_in,
                              void* d_out, int out_size, void* d_ws, size_t ws_size,
                              hipStream_t stream) {
  const float* x = (const float*)d_in[0];
  float* ws = (float*)d_ws;
  float* stats = ws;                                         //     1024 floats
  unsigned short* xf_b   = (unsigned short*)(ws + 1024);     //  2359296 shorts (1179648 f)
  unsigned short* xin_b  = (unsigned short*)(ws + 1180672);  //  4718592 shorts (2359296 f)
  unsigned short* sz_b   = (unsigned short*)(ws + 3539968);  //  4718592 shorts (2359296 f)
  float* dblC  = ws + 5899264;                               //   589824 f
  float* dts   = ws + 6489088;                               //   294912 f
  unsigned short* hlb    = (unsigned short*)(ws + 6784000);  //  4718592 shorts; dead after scan2bc -> inter
  unsigned short* hib    = (unsigned short*)(ws + 9143296);  //  4718592 shorts
  float2* gah  = (float2*)(ws + 11502592);                   //   196608 float2 (393216 f)
  unsigned short* wb     = (unsigned short*)(ws + 11895808); //    69632 shorts (34816 f)
  unsigned short* y1b    = (unsigned short*)(ws + 11930624); //  4718592 shorts (2359296 f)
  unsigned short* epb    = (unsigned short*)(ws + 14289920); //  4718592 shorts (2359296 f)
  float* prep  = ws + 16649216;                              //     4608 f (2 layers x 2304)
  float* partials = ws + 16653824;                           //   294912 f (2304 blocks x 128)
  float* inter = (float*)hlb;  // hlb dead after k_scan2bc; scanCO(L0) writes it; L1 consumes
                               // it in fusein BEFORE scanAX(L1) rewrites hlb.
  float* outp  = (float*)d_out;

  k_cvt<<<530, 256, 0, stream>>>((const float*)d_in[3], (const float*)d_in[6],
                                 (const float*)d_in[11], (const float*)d_in[13],
                                 (const float*)d_in[17], (const float*)d_in[20],
                                 (const float*)d_in[25], (const float*)d_in[27],
                                 (const float*)d_in[9], (const float*)d_in[23],
                                 x, wb, prep, stats);

  const float* cur = x;
  for (int layer = 0; layer < 2; ++layer) {
    const int p0 = 1 + 14 * layer;
    const float* ln_g   = (const float*)d_in[p0 + 0];
    const float* ln_b   = (const float*)d_in[p0 + 1];
    const float* conv_w = (const float*)d_in[p0 + 3];
    const float* conv_b = (const float*)d_in[p0 + 4];
    const float* dt_w   = (const float*)d_in[p0 + 6];
    const float* dt_b   = (const float*)d_in[p0 + 7];
    const float* A_log  = (const float*)d_in[p0 + 8];
    const float* Dp     = (const float*)d_in[p0 + 9];
    const float* skip   = (const float*)d_in[p0 + 11];
    const float* pr_b   = (const float*)d_in[p0 + 13];
    const unsigned short* inw_b = wb + (size_t)layer * 34816;
    const unsigned short* xpw_b = inw_b + 16384;
    const unsigned short* ow_b  = inw_b + 22528;
    const unsigned short* pw_b  = inw_b + 30720;
    const float* prepL = prep + (size_t)layer * 2304;
    float* dst = (layer == 0) ? inter : outp;

    k_fusein <<<BB * NT, 256, 0, stream>>>(cur, stats, ln_g, ln_b, inw_b, xf_b, xin_b, sz_b);
    k_scanAX <<<BB * GCH, 128, 0, stream>>>(xin_b, conv_w, conv_b, xpw_b, A_log, prepL,
                                            dt_w, dt_b, Dp, dblC, dts, hlb, y1b, epb);
    k_scan2a <<<(NG * NSEQ) / 256, 256, 0, stream>>>(dts, hlb, prepL, gah);
    k_scan2bc<<<(NG * NSEQ) / 256, 256, 0, stream>>>(dts, hlb, gah, prepL, hib);
    k_scanCO <<<BB * GCH, 128, 0, stream>>>(dblC, sz_b, y1b, epb, A_log, prepL, hib,
                                            ow_b, xf_b, skip, pw_b, pr_b, x, partials,
                                            dst, layer);
    if (layer == 0)
      k_statfin<<<BB * CC, 64, 0, stream>>>(partials, stats);
    cur = inter;
  }
}

// Round 21
// 196.150 us; speedup vs baseline: 1.0073x; 1.0073x over previous
//
#include <hip/hip_runtime.h>
#include <math.h>

#define BB 4
#define CC 64
#define DI 128
#define NS 16
#define LL 9216
#define NT (LL / 64)

// scan decomposition
#define GCH 576
#define LCH 16
#define NSEQ 8192      // B*DI*NS
#define SD  512        // B*DI
#define NG 24
#define GS 24          // NG*GS == GCH

typedef __attribute__((ext_vector_type(8))) short bf16x8;
typedef __attribute__((ext_vector_type(4))) float fx4;
#define MFMA16 __builtin_amdgcn_mfma_f32_16x16x32_bf16

static __device__ __forceinline__ unsigned short f2b(float f) {
  unsigned u = __float_as_uint(f);
  u += 0x7fffu + ((u >> 16) & 1u);
  return (unsigned short)(u >> 16);
}
static __device__ __forceinline__ float b2f(unsigned short s) {
  return __uint_as_float(((unsigned)s) << 16);
}
static __device__ __forceinline__ float silu_f(float x) {
  return x / (1.f + __expf(-x));
}

// powers of e1: a[n] = e1^(n+1)
static __device__ __forceinline__ void powers16(float e1, float* a) {
  float p2 = e1 * e1, p4 = p2 * p2, p8 = p4 * p4;
  a[0] = e1;      a[1] = p2;      a[2] = p2 * e1;      a[3] = p4;
  a[4] = p4 * e1; a[5] = p4 * p2; a[6] = p4 * p2 * e1; a[7] = p8;
  a[8] = p8 * e1; a[9] = p8 * p2; a[10] = p8 * p2 * e1; a[11] = p8 * p4;
  a[12] = p8 * p4 * e1; a[13] = p8 * p4 * p2; a[14] = p8 * p4 * p2 * e1; a[15] = p8 * p8;
}

// dtv = softplus(v); a[16] decay factors. aone: A0==-1 -> e1=sigmoid(-v) free.
static __device__ __forceinline__ float dt_and_a(float v, float A0, bool aone, bool afast,
                                                 const float* __restrict__ Alog, int d,
                                                 float* a) {
  float em = __expf(-fabsf(v));
  float t = 1.f + em;
  float dtv = fmaxf(v, 0.f) + __logf(t);
  if (aone) {
    float e1 = ((v >= 0.f) ? em : 1.f) / t;   // == exp(-dtv)
    powers16(e1, a);
  } else if (afast) {
    powers16(__expf(dtv * A0), a);
  } else {
    #pragma unroll
    for (int n = 0; n < 16; ++n) a[n] = __expf(dtv * -__expf(Alog[d * NS + n]));
  }
  return dtv;
}

// ---- weight bf16 conversion + per-layer A precompute + L0 instance-norm stats ----
__global__ __launch_bounds__(256) void k_cvt(const float* __restrict__ inw1, const float* __restrict__ xpw1,
                                             const float* __restrict__ ow1, const float* __restrict__ pw1,
                                             const float* __restrict__ inw2, const float* __restrict__ xpw2,
                                             const float* __restrict__ ow2, const float* __restrict__ pw2,
                                             const float* __restrict__ alog1, const float* __restrict__ alog2,
                                             const float* __restrict__ x,
                                             unsigned short* __restrict__ wb,
                                             float* __restrict__ prep,
                                             float* __restrict__ stats) {
  int blk = blockIdx.x;
  int tid = threadIdx.x;
  if (blk >= 274) {
    int bc = blk - 274;
    const float* row = x + (size_t)bc * LL;
    float s = 0.f, s2 = 0.f;
    for (int i = tid; i < LL; i += 256) {
      float v = row[i];
      s += v; s2 += v * v;
    }
    #pragma unroll
    for (int o = 32; o > 0; o >>= 1) {
      s += __shfl_down(s, o);
      s2 += __shfl_down(s2, o);
    }
    __shared__ float red[8];
    int w = tid >> 6;
    if ((tid & 63) == 0) { red[w] = s; red[4 + w] = s2; }
    __syncthreads();
    if (tid == 0) {
      float S = red[0] + red[1] + red[2] + red[3];
      float S2 = red[4] + red[5] + red[6] + red[7];
      float m = S * (1.f / LL);
      float var = S2 * (1.f / LL) - m * m;
      stats[bc * 2] = m;
      stats[bc * 2 + 1] = rsqrtf(var + 1e-5f);
    }
    return;
  }
  if (blk >= 272) {
    int layer = blk - 272;
    const float* alog = layer ? alog2 : alog1;
    float* pr = prep + layer * 2304;
    #pragma unroll
    for (int j = 0; j < 8; ++j) {
      int e = tid + 256 * j;
      pr[e] = -__expf(alog[e]);
    }
    if (tid < 128) {
      int d = tid;
      float A0 = -__expf(alog[d * NS]);
      bool afast = true;
      #pragma unroll
      for (int n = 1; n < 16; ++n) {
        float An = -__expf(alog[d * NS + n]);
        afast = afast && (fabsf(An - A0 * (float)(n + 1)) <= 1e-3f * (float)(n + 1) * fabsf(A0));
      }
      bool aone = afast && (A0 == -1.0f);
      pr[2048 + d] = A0;
      pr[2176 + d] = aone ? 2.f : (afast ? 1.f : 0.f);
    }
    return;
  }
  int idx = blk * 256 + tid;
  int layer = idx >= 34816;
  int e = idx - layer * 34816;
  const float* inw = layer ? inw2 : inw1;
  const float* xpw = layer ? xpw2 : xpw1;
  const float* ow = layer ? ow2 : ow1;
  const float* pw = layer ? pw2 : pw1;
  float v;
  if (e < 16384) v = inw[e];
  else if (e < 22528) { int t = e - 16384; int r = t >> 7, c = t & 127; v = (r < 36) ? xpw[r * 128 + c] : 0.f; }
  else if (e < 30720) v = ow[e - 22528];
  else v = pw[e - 30720];
  wb[idx] = f2b(v);
}

// ---- statfin: reduce per-block channel partials -> stats for layer 1 ----
__global__ __launch_bounds__(64) void k_statfin(const float* __restrict__ partials,
                                                float* __restrict__ stats) {
  int bc = blockIdx.x;
  int b = bc >> 6, c = bc & 63;
  int t = threadIdx.x;
  float S = 0.f, S2 = 0.f;
  for (int g = t; g < GCH; g += 64) {
    size_t pbase = ((size_t)(b * GCH + g)) * 128 + c * 2;
    S += partials[pbase];
    S2 += partials[pbase + 1];
  }
  #pragma unroll
  for (int o = 32; o > 0; o >>= 1) {
    S += __shfl_down(S, o);
    S2 += __shfl_down(S2, o);
  }
  if (t == 0) {
    float m = S * (1.f / LL);
    float var = S2 * (1.f / LL) - m * m;
    stats[bc * 2] = m;
    stats[bc * 2 + 1] = rsqrtf(var + 1e-5f);
  }
}

// ---- fused: transpose + IN + relu + LN + in-proj MFMA -> xf_b, xin_b, sz_b=silu(z) ----
__global__ __launch_bounds__(256) void k_fusein(const float* __restrict__ p,
                                                const float* __restrict__ stats,
                                                const float* __restrict__ g,
                                                const float* __restrict__ be,
                                                const unsigned short* __restrict__ w_b,
                                                unsigned short* __restrict__ xf_b,
                                                unsigned short* __restrict__ xin_b,
                                                unsigned short* __restrict__ sz_b) {
  int b = blockIdx.x / NT;
  int l0 = (blockIdx.x % NT) * 64;
  __shared__ float T[64][65];
  __shared__ unsigned short Tb[64][72];
  int li = threadIdx.x & 63;
  int c0 = threadIdx.x >> 6;
  #pragma unroll
  for (int j = 0; j < 16; ++j) {
    int c = c0 * 16 + j;
    float m = stats[(b * CC + c) * 2];
    float rs = stats[(b * CC + c) * 2 + 1];
    float v = p[((size_t)(b * CC + c)) * LL + l0 + li];
    T[li][c] = fmaxf((v - m) * rs, 0.f);
  }
  __syncthreads();
  {
    int row = threadIdx.x >> 2, part = threadIdx.x & 3;
    int ch0 = part * 16;
    float s = 0.f, s2 = 0.f;
    #pragma unroll
    for (int j = 0; j < 16; ++j) {
      float v = T[row][ch0 + j];
      s += v; s2 += v * v;
    }
    s += __shfl_xor(s, 1); s2 += __shfl_xor(s2, 1);
    s += __shfl_xor(s, 2); s2 += __shfl_xor(s2, 2);
    float m = s * (1.f / 64.f);
    float var = s2 * (1.f / 64.f) - m * m;
    float rs = rsqrtf(var + 1e-5f);
    size_t off0 = ((size_t)b * LL + l0 + row) * CC + ch0;
    #pragma unroll
    for (int j4 = 0; j4 < 4; ++j4) {
      float4 v4 = *(float4*)&T[row][ch0 + j4 * 4];
      xf_b[off0 + j4 * 4 + 0] = f2b(v4.x);
      xf_b[off0 + j4 * 4 + 1] = f2b(v4.y);
      xf_b[off0 + j4 * 4 + 2] = f2b(v4.z);
      xf_b[off0 + j4 * 4 + 3] = f2b(v4.w);
      float4 g4 = *(const float4*)&g[ch0 + j4 * 4];
      float4 b4 = *(const float4*)&be[ch0 + j4 * 4];
      Tb[row][ch0 + j4 * 4 + 0] = f2b((v4.x - m) * rs * g4.x + b4.x);
      Tb[row][ch0 + j4 * 4 + 1] = f2b((v4.y - m) * rs * g4.y + b4.y);
      Tb[row][ch0 + j4 * 4 + 2] = f2b((v4.z - m) * rs * g4.z + b4.z);
      Tb[row][ch0 + j4 * 4 + 3] = f2b((v4.w - m) * rs * g4.w + b4.w);
    }
  }
  __syncthreads();
  int lane = threadIdx.x & 63;
  int wv = threadIdx.x >> 6;
  int lr = lane & 15, kg = lane >> 4;
  int m0 = wv * 16;
  int rowg0 = blockIdx.x * 64 + m0;
  bf16x8 a0 = *(const bf16x8*)&Tb[m0 + lr][kg * 8];
  bf16x8 a1 = *(const bf16x8*)&Tb[m0 + lr][32 + kg * 8];
  #pragma unroll
  for (int nt = 0; nt < 16; ++nt) {
    bf16x8 b0 = *(const bf16x8*)&w_b[(size_t)(nt * 16 + lr) * CC + kg * 8];
    bf16x8 b1 = *(const bf16x8*)&w_b[(size_t)(nt * 16 + lr) * CC + 32 + kg * 8];
    fx4 c = {0.f, 0.f, 0.f, 0.f};
    c = MFMA16(a0, b0, c, 0, 0, 0);
    c = MFMA16(a1, b1, c, 0, 0, 0);
    #pragma unroll
    for (int r = 0; r < 4; ++r) {
      int row = rowg0 + kg * 4 + r, col = nt * 16 + lr;
      if (col < 128) xin_b[(size_t)row * DI + col] = f2b(c[r]);
      else           sz_b[(size_t)row * DI + col - 128] = f2b(silu_f(c[r]));
    }
  }
}

// ---- scanAX: LDS-staged xin window + split-K x-proj MFMA + local scan ----
__global__ __launch_bounds__(128) void k_scanAX(const unsigned short* __restrict__ xin_b,
                                                const float* __restrict__ cw,
                                                const float* __restrict__ cb,
                                                const unsigned short* __restrict__ xpw_b,
                                                const float* __restrict__ Alog,
                                                const float* __restrict__ prep,
                                                const float* __restrict__ dtw,
                                                const float* __restrict__ dtbp,
                                                const float* __restrict__ Dp,
                                                float* __restrict__ dblC,
                                                float* __restrict__ dts,
                                                unsigned short* __restrict__ hlb,
                                                unsigned short* __restrict__ y1b,
                                                unsigned short* __restrict__ dtpreb) {
  int g = blockIdx.x % GCH;
  int b = blockIdx.x / GCH;
  __shared__ float dblP[2][16][40];
  __shared__ unsigned short xcS[16][136];
  __shared__ unsigned short xinS[19][136];
  int wv = threadIdx.x >> 6, lane = threadIdx.x & 63;
  int lr = lane & 15, kg = lane >> 4;
  // stage 19-row window (rows g*16-3 .. g*16+15; zeros when l<0)
  {
    const bf16x8 zv8 = {0, 0, 0, 0, 0, 0, 0, 0};
    for (int e = threadIdx.x; e < 304; e += 128) {
      int row = e >> 4, c8 = e & 15;
      int gl = g * LCH - 3 + row;   // in-batch l
      bf16x8 v = (gl >= 0) ? *(const bf16x8*)&xin_b[((size_t)b * LL + gl) * DI + c8 * 8] : zv8;
      *(bf16x8*)&xinS[row][c8 * 8] = v;
    }
  }
  __syncthreads();
  {
    fx4 acc[3];
    #pragma unroll
    for (int nt = 0; nt < 3; ++nt) acc[nt] = (fx4){0.f, 0.f, 0.f, 0.f};
    #pragma unroll
    for (int kk = 0; kk < 2; ++kk) {
      int cbase = (wv * 2 + kk) * 32 + kg * 8;
      bf16x8 x3 = *(const bf16x8*)&xinS[3 + lr][cbase];
      bf16x8 x2 = *(const bf16x8*)&xinS[2 + lr][cbase];
      bf16x8 x1 = *(const bf16x8*)&xinS[1 + lr][cbase];
      bf16x8 x0 = *(const bf16x8*)&xinS[0 + lr][cbase];
      bf16x8 a;
      #pragma unroll
      for (int e = 0; e < 8; ++e) {
        int dd = cbase + e;
        float4 w4 = *(const float4*)&cw[dd * 4];
        float v = cb[dd] + b2f((unsigned short)x0[e]) * w4.x + b2f((unsigned short)x1[e]) * w4.y
                + b2f((unsigned short)x2[e]) * w4.z + b2f((unsigned short)x3[e]) * w4.w;
        a[e] = (short)f2b(silu_f(v));
      }
      *(bf16x8*)&xcS[lr][cbase] = a;
      #pragma unroll
      for (int nt = 0; nt < 3; ++nt) {
        bf16x8 bfr = *(const bf16x8*)&xpw_b[(size_t)(nt * 16 + lr) * DI + cbase];
        acc[nt] = MFMA16(a, bfr, acc[nt], 0, 0, 0);
      }
    }
    #pragma unroll
    for (int nt = 0; nt < 3; ++nt)
      #pragma unroll
      for (int r = 0; r < 4; ++r) {
        int col = nt * 16 + lr;
        if (col < 36) dblP[wv][kg * 4 + r][col] = acc[nt][r];
      }
  }
  __syncthreads();
  for (int e = threadIdx.x; e < 576; e += 128) {
    int r = e / 36, c = e - r * 36;
    dblP[0][r][c] += dblP[1][r][c];
  }
  __syncthreads();
  {
    size_t cbase16 = ((size_t)b * LL + g * LCH) * 16;
    #pragma unroll
    for (int j = 0; j < 2; ++j) {
      int e = threadIdx.x + 128 * j;
      dblC[cbase16 + e] = dblP[0][e >> 4][20 + (e & 15)];
    }
  }
  int d = threadIdx.x;
  float A0 = prep[2048 + d];
  int fl = (int)prep[2176 + d];
  bool afast = fl >= 1;
  bool aone = fl == 2;
  float4 w4 = *(const float4*)&dtw[d * 4];
  float dtbv = dtbp[d];
  float Dv = Dp[d];
  float h[16];
  #pragma unroll
  for (int n = 0; n < 16; ++n) h[n] = 0.f;
  float dtsum = 0.f;
  size_t sbase = ((size_t)b * LL + g * LCH) * DI + d;
  #pragma unroll 4
  for (int l = 0; l < LCH; ++l) {
    float xcv = b2f(xcS[l][d]);
    float4 qv = *(float4*)&dblP[0][l][0];
    float v = dtbv + qv.x * w4.x + qv.y * w4.y + qv.z * w4.z + qv.w * w4.w;
    float a[16];
    float dtv = dt_and_a(v, A0, aone, afast, Alog, d, a);
    float dx = dtv * xcv;
    dtsum += dtv;
    float4 b0 = *(float4*)&dblP[0][l][4];
    float4 b1 = *(float4*)&dblP[0][l][8];
    float4 b2 = *(float4*)&dblP[0][l][12];
    float4 b3 = *(float4*)&dblP[0][l][16];
    h[0]  = a[0]  * h[0]  + dx * b0.x;  h[1]  = a[1]  * h[1]  + dx * b0.y;
    h[2]  = a[2]  * h[2]  + dx * b0.z;  h[3]  = a[3]  * h[3]  + dx * b0.w;
    h[4]  = a[4]  * h[4]  + dx * b1.x;  h[5]  = a[5]  * h[5]  + dx * b1.y;
    h[6]  = a[6]  * h[6]  + dx * b1.z;  h[7]  = a[7]  * h[7]  + dx * b1.w;
    h[8]  = a[8]  * h[8]  + dx * b2.x;  h[9]  = a[9]  * h[9]  + dx * b2.y;
    h[10] = a[10] * h[10] + dx * b2.z;  h[11] = a[11] * h[11] + dx * b2.w;
    h[12] = a[12] * h[12] + dx * b3.x;  h[13] = a[13] * h[13] + dx * b3.y;
    h[14] = a[14] * h[14] + dx * b3.z;  h[15] = a[15] * h[15] + dx * b3.w;
    float4 cc0 = *(float4*)&dblP[0][l][20];
    float4 cc1 = *(float4*)&dblP[0][l][24];
    float4 cc2 = *(float4*)&dblP[0][l][28];
    float4 cc3 = *(float4*)&dblP[0][l][32];
    float y0 = h[0] * cc0.x + h[1] * cc0.y + h[2] * cc0.z + h[3] * cc0.w;
    float y1 = h[4] * cc1.x + h[5] * cc1.y + h[6] * cc1.z + h[7] * cc1.w;
    float y2 = h[8] * cc2.x + h[9] * cc2.y + h[10] * cc2.z + h[11] * cc2.w;
    float y3 = h[12] * cc3.x + h[13] * cc3.y + h[14] * cc3.z + h[15] * cc3.w;
    y1b[sbase + (size_t)l * DI] = f2b((y0 + y1) + (y2 + y3) + Dv * xcv);
    dtpreb[sbase + (size_t)l * DI] = f2b(dtsum);
  }
  dts[(size_t)g * SD + b * DI + d] = dtsum;
  size_t o = (size_t)g * NSEQ + ((size_t)b * DI + d) * NS;
  bf16x8 hv0, hv1;
  #pragma unroll
  for (int n = 0; n < 8; ++n) { hv0[n] = (short)f2b(h[n]); hv1[n] = (short)f2b(h[8 + n]); }
  *(bf16x8*)&hlb[o] = hv0;
  *(bf16x8*)&hlb[o + 8] = hv1;
}

// ---- scan2a: per-group aggregates; writes packed float2 (A,H) ----
__global__ __launch_bounds__(256) void k_scan2a(const float* __restrict__ dts,
                                                const unsigned short* __restrict__ hlb,
                                                const float* __restrict__ prep,
                                                float2* __restrict__ gah) {
  int t = blockIdx.x * 256 + threadIdx.x;   // < NG*NSEQ
  int grp = t >> 13, seq = t & (NSEQ - 1);
  int sd = seq >> 4;
  float An = prep[seq & (DI * NS - 1)];
  float A = 1.f, H = 0.f;
  int c0 = grp * GS;
  #pragma unroll 4
  for (int c = 0; c < GS; ++c) {
    float a = __expf(An * dts[(size_t)(c0 + c) * SD + sd]);
    H = a * H + b2f(hlb[(size_t)(c0 + c) * NSEQ + seq]);
    A *= a;
  }
  gah[t] = make_float2(A, H);
}

// ---- scan2bc: redundant group-prefix + chunk carries (hi out bf16) ----
__global__ __launch_bounds__(256) void k_scan2bc(const float* __restrict__ dts,
                                                 const unsigned short* __restrict__ hlb,
                                                 const float2* __restrict__ gah,
                                                 const float* __restrict__ prep,
                                                 unsigned short* __restrict__ hib) {
  int t = blockIdx.x * 256 + threadIdx.x;   // < NG*NSEQ
  int grp = t >> 13, seq = t & (NSEQ - 1);
  int sd = seq >> 4;
  float An = prep[seq & (DI * NS - 1)];
  float h = 0.f;
  for (int gg = 0; gg < grp; ++gg) {
    float2 ah = gah[gg * NSEQ + seq];
    h = ah.x * h + ah.y;
  }
  int c0 = grp * GS;
  #pragma unroll 4
  for (int c = 0; c < GS; ++c) {
    float a = __expf(An * dts[(size_t)(c0 + c) * SD + sd]);
    hib[(size_t)(c0 + c) * NSEQ + seq] = f2b(h);
    h = a * h + b2f(hlb[(size_t)(c0 + c) * NSEQ + seq]);
  }
}

// ---- scanCO: y = y1 + C.diag(exp(A dtpre)).hi; *silu(z); out/pr-proj;
//      emits per-block channel (sum,sumsq) partials when addid==0 ----
__global__ __launch_bounds__(128) void k_scanCO(const float* __restrict__ dblC,
                                                const unsigned short* __restrict__ sz_b,
                                                const unsigned short* __restrict__ y1b,
                                                const unsigned short* __restrict__ dtpreb,
                                                const float* __restrict__ Alog,
                                                const float* __restrict__ prep,
                                                const unsigned short* __restrict__ hib,
                                                const unsigned short* __restrict__ ow_b,
                                                const unsigned short* __restrict__ xf_b,
                                                const float* __restrict__ skipv,
                                                const unsigned short* __restrict__ pw_b,
                                                const float* __restrict__ pb,
                                                const float* __restrict__ ident,
                                                float* __restrict__ partials,
                                                float* __restrict__ dst, int addid) {
  int g = blockIdx.x % GCH;
  int b = blockIdx.x / GCH;
  int d = threadIdx.x;
  __shared__ float Cms[LCH * NS];
  __shared__ unsigned short yS[16][136];
  __shared__ unsigned short tmpS[16][72];
  {
    int tid = threadIdx.x;
    size_t cb16 = ((size_t)b * LL + g * LCH) * 16;
    if (tid < 64) *(float4*)&Cms[tid * 4] = *(const float4*)&dblC[cb16 + tid * 4];
  }
  float A0 = prep[2048 + d];
  bool afast = ((int)prep[2176 + d]) >= 1;
  __syncthreads();
  size_t o = (size_t)g * NSEQ + ((size_t)b * DI + d) * NS;
  float hiR[16];
  {
    bf16x8 h0 = *(const bf16x8*)&hib[o];
    bf16x8 h1 = *(const bf16x8*)&hib[o + 8];
    #pragma unroll
    for (int n = 0; n < 8; ++n) {
      hiR[n] = b2f((unsigned short)h0[n]);
      hiR[8 + n] = b2f((unsigned short)h1[n]);
    }
  }
  size_t base = ((size_t)b * LL + g * LCH) * DI + d;
  #pragma unroll 4
  for (int l = 0; l < LCH; ++l) {
    float dtpre = b2f(dtpreb[base + (size_t)l * DI]);
    float y1v = b2f(y1b[base + (size_t)l * DI]);
    float sg = b2f(sz_b[base + (size_t)l * DI]);
    float pw[16];
    if (afast) {
      powers16(__expf(A0 * dtpre), pw);
    } else {
      #pragma unroll
      for (int n = 0; n < 16; ++n) pw[n] = __expf(-__expf(Alog[d * NS + n]) * dtpre);
    }
    float4 c0 = *(float4*)&Cms[l * 16];
    float4 c1 = *(float4*)&Cms[l * 16 + 4];
    float4 c2 = *(float4*)&Cms[l * 16 + 8];
    float4 c3 = *(float4*)&Cms[l * 16 + 12];
    float s0 = c0.x * pw[0] * hiR[0] + c0.y * pw[1] * hiR[1] + c0.z * pw[2] * hiR[2] + c0.w * pw[3] * hiR[3];
    float s1 = c1.x * pw[4] * hiR[4] + c1.y * pw[5] * hiR[5] + c1.z * pw[6] * hiR[6] + c1.w * pw[7] * hiR[7];
    float s2 = c2.x * pw[8] * hiR[8] + c2.y * pw[9] * hiR[9] + c2.z * pw[10] * hiR[10] + c2.w * pw[11] * hiR[11];
    float s3 = c3.x * pw[12] * hiR[12] + c3.y * pw[13] * hiR[13] + c3.z * pw[14] * hiR[14] + c3.w * pw[15] * hiR[15];
    float yv = y1v + ((s0 + s1) + (s2 + s3));
    yS[l][d] = f2b(yv * sg);
  }
  __syncthreads();
  int lane = threadIdx.x & 63;
  int lr = lane & 15, kg = lane >> 4;
  int lw = threadIdx.x >> 6;
  {
    fx4 oacc[2];
    oacc[0] = (fx4){0.f, 0.f, 0.f, 0.f};
    oacc[1] = (fx4){0.f, 0.f, 0.f, 0.f};
    #pragma unroll
    for (int ks = 0; ks < 4; ++ks) {
      int cbase = ks * 32 + kg * 8;
      bf16x8 a = *(const bf16x8*)&yS[lr][cbase];
      #pragma unroll
      for (int j = 0; j < 2; ++j) {
        int nt = lw * 2 + j;
        bf16x8 bfr = *(const bf16x8*)&ow_b[(size_t)(nt * 16 + lr) * DI + cbase];
        oacc[j] = MFMA16(a, bfr, oacc[j], 0, 0, 0);
      }
    }
    float sk = skipv[0];
    #pragma unroll
    for (int j = 0; j < 2; ++j) {
      int nt = lw * 2 + j;
      #pragma unroll
      for (int r = 0; r < 4; ++r) {
        int rowl = kg * 4 + r, col = nt * 16 + lr;
        size_t grow = (size_t)b * LL + g * LCH + rowl;
        tmpS[rowl][col] = f2b(oacc[j][r] + sk * b2f(xf_b[grow * CC + col]));
      }
    }
  }
  __syncthreads();
  {
    fx4 pacc[2];
    pacc[0] = (fx4){0.f, 0.f, 0.f, 0.f};
    pacc[1] = (fx4){0.f, 0.f, 0.f, 0.f};
    #pragma unroll
    for (int ks = 0; ks < 2; ++ks) {
      int cbase = ks * 32 + kg * 8;
      bf16x8 bfrag = *(const bf16x8*)&tmpS[lr][cbase];
      #pragma unroll
      for (int j = 0; j < 2; ++j) {
        int ct = lw * 2 + j;
        bf16x8 a = *(const bf16x8*)&pw_b[(size_t)(ct * 16 + lr) * CC + cbase];
        pacc[j] = MFMA16(a, bfrag, pacc[j], 0, 0, 0);
      }
    }
    #pragma unroll
    for (int j = 0; j < 2; ++j) {
      int ct = lw * 2 + j;
      #pragma unroll
      for (int r = 0; r < 4; ++r) {
        int c = ct * 16 + kg * 4 + r;
        int lpos = g * LCH + lr;
        size_t off = ((size_t)(b * CC + c)) * LL + lpos;
        float val = pacc[j][r] + pb[c];
        if (addid) {
          dst[off] = val + ident[off];
        } else {
          dst[off] = val;
          float s = val, s2 = val * val;
          s += __shfl_xor(s, 1); s2 += __shfl_xor(s2, 1);
          s += __shfl_xor(s, 2); s2 += __shfl_xor(s2, 2);
          s += __shfl_xor(s, 4); s2 += __shfl_xor(s2, 4);
          s += __shfl_xor(s, 8); s2 += __shfl_xor(s2, 8);
          if (lr == 0) {
            size_t pbase = ((size_t)(b * GCH + g)) * 128 + c * 2;
            partials[pbase] = s;
            partials[pbase + 1] = s2;
          }
        }
      }
    }
  }
}

extern "C" void kernel_launch(void* const* d_in, const int* in_sizes, int n_in,
                              void* d_out, int out_size, void* d_ws, size_t ws_size,
                              hipStream_t stream) {
  const float* x = (const float*)d_in[0];
  float* ws = (float*)d_ws;
  float* stats = ws;                                         //     1024 floats
  unsigned short* xf_b   = (unsigned short*)(ws + 1024);     //  2359296 shorts (1179648 f)
  unsigned short* xin_b  = (unsigned short*)(ws + 1180672);  //  4718592 shorts (2359296 f)
  unsigned short* sz_b   = (unsigned short*)(ws + 3539968);  //  4718592 shorts (2359296 f)
  float* dblC  = ws + 5899264;                               //   589824 f
  float* dts   = ws + 6489088;                               //   294912 f
  unsigned short* hlb    = (unsigned short*)(ws + 6784000);  //  4718592 shorts; dead after scan2bc -> inter
  unsigned short* hib    = (unsigned short*)(ws + 9143296);  //  4718592 shorts
  float2* gah  = (float2*)(ws + 11502592);                   //   196608 float2 (393216 f)
  unsigned short* wb     = (unsigned short*)(ws + 11895808); //    69632 shorts (34816 f)
  unsigned short* y1b    = (unsigned short*)(ws + 11930624); //  4718592 shorts (2359296 f)
  unsigned short* dtpreb = (unsigned short*)(ws + 14289920); //  4718592 shorts (2359296 f)
  float* prep  = ws + 16649216;                              //     4608 f (2 layers x 2304)
  float* partials = ws + 16653824;                           //   294912 f (2304 blocks x 128)
  float* inter = (float*)hlb;  // hlb dead after k_scan2bc; scanCO(L0) writes it; L1 consumes
                               // it in fusein BEFORE scanAX(L1) rewrites hlb.
  float* outp  = (float*)d_out;

  k_cvt<<<530, 256, 0, stream>>>((const float*)d_in[3], (const float*)d_in[6],
                                 (const float*)d_in[11], (const float*)d_in[13],
                                 (const float*)d_in[17], (const float*)d_in[20],
                                 (const float*)d_in[25], (const float*)d_in[27],
                                 (const float*)d_in[9], (const float*)d_in[23],
                                 x, wb, prep, stats);

  const float* cur = x;
  for (int layer = 0; layer < 2; ++layer) {
    const int p0 = 1 + 14 * layer;
    const float* ln_g   = (const float*)d_in[p0 + 0];
    const float* ln_b   = (const float*)d_in[p0 + 1];
    const float* conv_w = (const float*)d_in[p0 + 3];
    const float* conv_b = (const float*)d_in[p0 + 4];
    const float* dt_w   = (const float*)d_in[p0 + 6];
    const float* dt_b   = (const float*)d_in[p0 + 7];
    const float* A_log  = (const float*)d_in[p0 + 8];
    const float* Dp     = (const float*)d_in[p0 + 9];
    const float* skip   = (const float*)d_in[p0 + 11];
    const float* pr_b   = (const float*)d_in[p0 + 13];
    const unsigned short* inw_b = wb + (size_t)layer * 34816;
    const unsigned short* xpw_b = inw_b + 16384;
    const unsigned short* ow_b  = inw_b + 22528;
    const unsigned short* pw_b  = inw_b + 30720;
    const float* prepL = prep + (size_t)layer * 2304;
    float* dst = (layer == 0) ? inter : outp;

    k_fusein <<<BB * NT, 256, 0, stream>>>(cur, stats, ln_g, ln_b, inw_b, xf_b, xin_b, sz_b);
    k_scanAX <<<BB * GCH, 128, 0, stream>>>(xin_b, conv_w, conv_b, xpw_b, A_log, prepL,
                                            dt_w, dt_b, Dp, dblC, dts, hlb, y1b, dtpreb);
    k_scan2a <<<(NG * NSEQ) / 256, 256, 0, stream>>>(dts, hlb, prepL, gah);
    k_scan2bc<<<(NG * NSEQ) / 256, 256, 0, stream>>>(dts, hlb, gah, prepL, hib);
    k_scanCO <<<BB * GCH, 128, 0, stream>>>(dblC, sz_b, y1b, dtpreb, A_log, prepL, hib,
                                            ow_b, xf_b, skip, pw_b, pr_b, x, partials,
                                            dst, layer);
    if (layer == 0)
      k_statfin<<<BB * CC, 64, 0, stream>>>(partials, stats);
    cur = inter;
  }
}